// Round 1
// baseline (1452.927 us; speedup 1.0000x reference)
//
#include <hip/hip_runtime.h>
#include <stdint.h>

#define NN 200000      // nodes
#define HH 256         // hidden
#define BB 512         // batch / steps
#define NEGS 5
#define NSLOT 22       // 17 written rows (event + 16 neighbors) + 5 negative (read-only)
#define TOTSLOT (BB*NSLOT)   // 11264
#define COPY_BLOCKS 2048
#define TD_MAX_F 86400.0f

__device__ __forceinline__ float hawkes_dev(float dot, float td, float bo, float wt,
                                            float alpha, float psi) {
    float g = dot + bo + alpha * expf(-wt * (td / TD_MAX_F));
    float gp = g / (psi + 1e-7f);
    gp = fminf(75.0f, fmaxf(-75.0f, gp));
    return psi * log1pf(expf(gp));
}

// Assign each unique touched row a compact id = winning slot index.
__global__ void k_assign(const int* __restrict__ u, const int* __restrict__ uneg,
                         int* __restrict__ map) {
    int s = blockIdx.x * 256 + threadIdx.x;
    if (s >= TOTSLOT) return;
    int t = s / NSLOT, j = s - t * NSLOT;
    int row = (j < 17) ? u[t * 17 + j] : uneg[t * NEGS + (j - 17)];
    atomicCAS(&map[row], -1, s);
}

// Resolve slot -> compact row; winners gather z0 row into compact buffer zc.
__global__ void k_prep(const int* __restrict__ u, const int* __restrict__ uneg,
                       const int* __restrict__ map, const float* __restrict__ z0,
                       float* __restrict__ zc, int* __restrict__ rrow) {
    int s = blockIdx.x;
    int t = s / NSLOT, j = s - t * NSLOT;
    int row = (j < 17) ? u[t * 17 + j] : uneg[t * NEGS + (j - 17)];
    int w = map[row];
    if (threadIdx.x == 0) rrow[s] = w;
    if (w == s) {
        const float4* src = (const float4*)(z0 + (size_t)row * HH);
        float4* dst = (float4*)(zc + (size_t)s * HH);
        dst[threadIdx.x] = src[threadIdx.x];   // 64 threads * 16B = 1KB row
    }
}

// Scatter final compact rows into z_final (after bulk copy + scan done).
__global__ void k_scatter(const int* __restrict__ u, const int* __restrict__ uneg,
                          const int* __restrict__ rrow, const float* __restrict__ zc,
                          float* __restrict__ outz) {
    int s = blockIdx.x;
    if (rrow[s] != s) return;   // not the winner for this row
    int t = s / NSLOT, j = s - t * NSLOT;
    int row = (j < 17) ? u[t * 17 + j] : uneg[t * NEGS + (j - 17)];
    const float4* src = (const float4*)(zc + (size_t)s * HH);
    float4* dst = (float4*)(outz + (size_t)row * HH);
    dst[threadIdx.x] = src[threadIdx.x];
}

// Blocks [0,512): one scan step each, ordered only by true row conflicts.
// Blocks [512, 512+COPY_BLOCKS): bulk copy z0 -> z_final region (overlapped).
__global__ __launch_bounds__(256, 2) void k_main(
    const int* __restrict__ u, const float* __restrict__ time_delta,
    const float* __restrict__ time_bar, const float* __restrict__ time_cur,
    const int* __restrict__ uneg, const float* __restrict__ z0,
    const float* __restrict__ W_h, const float* __restrict__ b_h,
    const float* __restrict__ W_e2n, const float* __restrict__ b_e2n,
    const float* __restrict__ W_re, const float* __restrict__ b_re,
    const float* __restrict__ W_rn, const float* __restrict__ b_rn,
    const float* __restrict__ W_t4, const float* __restrict__ b_t,
    const float* __restrict__ W_om, const float* __restrict__ b_om,
    const float* __restrict__ wt_p, const float* __restrict__ alpha_p,
    const float* __restrict__ psi_p,
    float* __restrict__ zc, const int* __restrict__ rrow,
    unsigned long long* __restrict__ done, float* __restrict__ out)
{
    if (blockIdx.x >= BB) {
        // bulk copy: z0 -> out z_final region, grid-stride float4
        const float4* src = (const float4*)z0;
        float4* dst = (float4*)(out + BB + BB * NEGS);
        size_t total4 = (size_t)NN * HH / 4;
        size_t idx = (size_t)(blockIdx.x - BB) * 256 + threadIdx.x;
        size_t stride = (size_t)COPY_BLOCKS * 256;
        for (size_t p = idx; p < total4; p += stride) dst[p] = src[p];
        return;
    }

    const int t = blockIdx.x;
    const int tid = threadIdx.x;
    const int lane = tid & 63, wv = tid >> 6;

    __shared__ int s_rows[NSLOT];
    __shared__ int s_cr[NSLOT];
    __shared__ unsigned long long s_dep[8];
    __shared__ float s_td[68];           // normalized time_delta (17x4)
    __shared__ float s_z[NSLOT][HH];     // 22.5 KB
    __shared__ float s_zbar[HH];
    __shared__ float s_part[6][4];

    if (tid < NSLOT) {
        int row = (tid < 17) ? u[t * 17 + tid] : uneg[t * NEGS + tid - 17];
        s_rows[tid] = row;
        s_cr[tid] = rrow[t * NSLOT + tid];
    }
    if (tid < 68) {
        const float tsd[4] = {50.0f, 7.0f, 15.0f, 15.0f};
        s_td[tid] = time_delta[t * 68 + tid] / tsd[tid & 3];
    }
    __syncthreads();

    // --- dependency bitmask over earlier steps: conflict iff shared row with a writer
    #pragma unroll
    for (int r = 0; r < 2; ++r) {
        int tp = tid + 256 * r;
        bool conf = false;
        if (tp < t) {
            int orow[NSLOT];
            #pragma unroll
            for (int j = 0; j < 17; ++j) orow[j] = u[tp * 17 + j];
            #pragma unroll
            for (int j = 0; j < NEGS; ++j) orow[17 + j] = uneg[tp * NEGS + j];
            #pragma unroll
            for (int a = 0; a < NSLOT; ++a) {
                int ra = s_rows[a];
                #pragma unroll
                for (int b = 0; b < NSLOT; ++b) {
                    if (ra == orow[b] && (a < 17 || b < 17)) conf = true;
                }
            }
        }
        unsigned long long m = __ballot(conf);
        if (lane == 0) s_dep[wv + 4 * r] = m;
    }

    // --- tfeat: thread i holds tfeat[j][i], j=0..16
    float4 wt4 = ((const float4*)W_t4)[tid];
    float bt = b_t[tid];
    float tf[17];
    #pragma unroll
    for (int j = 0; j < 17; ++j)
        tf[j] = bt + s_td[j*4]*wt4.x + s_td[j*4+1]*wt4.y + s_td[j*4+2]*wt4.z + s_td[j*4+3]*wt4.w;
    __syncthreads();

    // --- spin until all dependency steps committed
    if (tid == 0) {
        #pragma unroll
        for (int w = 0; w < 8; ++w) {
            unsigned long long need = s_dep[w];
            if (!need) continue;
            while ((__hip_atomic_load(&done[w], __ATOMIC_ACQUIRE,
                                      __HIP_MEMORY_SCOPE_AGENT) & need) != need)
                __builtin_amdgcn_s_sleep(1);
        }
    }
    __syncthreads();

    // --- load the 22 z rows (agent-scope so cross-XCD writes are seen)
    #pragma unroll
    for (int s = 0; s < NSLOT; ++s) {
        s_z[s][tid] = __hip_atomic_load(&zc[(size_t)s_cr[s] * HH + tid],
                                        __ATOMIC_RELAXED, __HIP_MEMORY_SCOPE_AGENT);
    }
    __syncthreads();
    float zb = 0.0f;
    #pragma unroll
    for (int j = 1; j <= 16; ++j) zb += s_z[j][tid];
    s_zbar[tid] = zb * 0.0625f;     // mean(z_nb) — mean commutes with W_h
    __syncthreads();

    // --- GEMVs: thread i = output feature i; W rows contiguous, z from LDS broadcast
    const float4* Wh4  = (const float4*)(W_h  + (size_t)tid * HH);
    const float4* Wre4 = (const float4*)(W_re + (size_t)tid * HH);
    const float4* Wen4 = (const float4*)(W_e2n+ (size_t)tid * HH);
    const float4* Wrn4 = (const float4*)(W_rn + (size_t)tid * HH);
    const float4* zb4  = (const float4*)s_zbar;
    const float4* eu4  = (const float4*)s_z[0];
    float ah = 0.0f, ae = 0.0f, an = 0.0f;
    #pragma unroll 4
    for (int k = 0; k < HH/4; ++k) {
        float4 a = Wh4[k], b = Wre4[k], c = Wen4[k];
        float4 z1 = zb4[k], z2 = eu4[k];
        ah += a.x*z1.x + a.y*z1.y + a.z*z1.z + a.w*z1.w;
        ae += b.x*z2.x + b.y*z2.y + b.z*z2.z + b.w*z2.w;
        an += c.x*z2.x + c.y*z2.y + c.z*z2.z + c.w*z2.w;
    }
    float accn[16];
    #pragma unroll
    for (int j = 0; j < 16; ++j) accn[j] = 0.0f;
    for (int k = 0; k < HH/4; ++k) {
        float4 wvv = Wrn4[k];
        #pragma unroll
        for (int j = 0; j < 16; ++j) {
            float4 zz = ((const float4*)s_z[1 + j])[k];   // LDS broadcast (same addr all lanes)
            accn[j] += wvv.x*zz.x + wvv.y*zz.y + wvv.z*zz.z + wvv.w*zz.w;
        }
    }
    float ev = ah + b_h[tid] + ae + b_re[tid] + tf[0];
    ev = 1.0f / (1.0f + expf(-ev));
    float base = an + b_e2n[tid] + b_rn[tid];

    // --- writes: neighbors (suppress all but last duplicate, event wins), event last
    #pragma unroll
    for (int j = 0; j < 16; ++j) {
        int row = s_rows[1 + j];
        bool wr = (row != s_rows[0]);
        #pragma unroll
        for (int j2 = j + 1; j2 < 16; ++j2) if (s_rows[1 + j2] == row) wr = false;
        if (wr) {
            float v = accn[j] + base + tf[1 + j];
            v = 1.0f / (1.0f + expf(-v));
            __hip_atomic_store(&zc[(size_t)s_cr[1 + j] * HH + tid], v,
                               __ATOMIC_RELAXED, __HIP_MEMORY_SCOPE_AGENT);
        }
    }
    __hip_atomic_store(&zc[(size_t)s_cr[0] * HH + tid], ev,
                       __ATOMIC_RELAXED, __HIP_MEMORY_SCOPE_AGENT);
    __syncthreads();      // vmcnt(0) drain for all threads' stores
    __threadfence();      // agent-scope fence
    if (tid == 0)
        __hip_atomic_fetch_or(&done[t >> 6], 1ull << (t & 63),
                              __ATOMIC_RELEASE, __HIP_MEMORY_SCOPE_AGENT);

    // --- hawkes outputs (post-commit; uses LDS copies of pre-update embeddings)
    float wom = W_om[tid];
    float pv[6];
    pv[0] = wom * s_z[0][tid];
    #pragma unroll
    for (int n = 1; n < 6; ++n) pv[n] = wom * s_z[16 + n][tid];
    #pragma unroll
    for (int off = 32; off > 0; off >>= 1) {
        #pragma unroll
        for (int n = 0; n < 6; ++n) pv[n] += __shfl_down(pv[n], off, 64);
    }
    if (lane == 0) {
        #pragma unroll
        for (int n = 0; n < 6; ++n) s_part[n][wv] = pv[n];
    }
    __syncthreads();
    if (tid < 6) {
        float dot = s_part[tid][0] + s_part[tid][1] + s_part[tid][2] + s_part[tid][3];
        float wt = wt_p[0], alpha = alpha_p[0], psi = psi_p[0], bo = b_om[0];
        float tc = time_cur[t];
        float td;
        if (tid == 0) td = tc - s_td[0];                       // ts_diff = t_cur - td_norm[0,0]
        else td = tc - time_bar[(size_t)t * NN + s_rows[16 + tid]];  // ts_neg
        float lam = hawkes_dev(dot, td, bo, wt, alpha, psi);
        if (tid == 0) out[t] = lam;
        else out[BB + t * NEGS + (tid - 1)] = lam / (float)NEGS;
    }
}

extern "C" void kernel_launch(void* const* d_in, const int* in_sizes, int n_in,
                              void* d_out, int out_size, void* d_ws, size_t ws_size,
                              hipStream_t stream) {
    (void)in_sizes; (void)n_in; (void)out_size; (void)ws_size;
    const int*   u          = (const int*)d_in[0];
    const float* time_delta = (const float*)d_in[1];
    const float* time_bar   = (const float*)d_in[2];
    const float* time_cur   = (const float*)d_in[3];
    const int*   uneg       = (const int*)d_in[6];
    const float* z0         = (const float*)d_in[7];
    const float* W_h   = (const float*)d_in[8];
    const float* b_h   = (const float*)d_in[9];
    const float* W_e2n = (const float*)d_in[10];
    const float* b_e2n = (const float*)d_in[11];
    const float* W_re  = (const float*)d_in[12];
    const float* b_re  = (const float*)d_in[13];
    const float* W_rn  = (const float*)d_in[14];
    const float* b_rn  = (const float*)d_in[15];
    const float* W_t   = (const float*)d_in[16];
    const float* b_t   = (const float*)d_in[17];
    const float* W_om  = (const float*)d_in[18];
    const float* b_om  = (const float*)d_in[19];
    const float* wtp   = (const float*)d_in[20];
    const float* alp   = (const float*)d_in[21];
    const float* psip  = (const float*)d_in[22];
    float* out = (float*)d_out;

    char* ws = (char*)d_ws;
    float* zc  = (float*)ws;                                   // 11264*256*4 = 11,534,336 B
    size_t off = (size_t)TOTSLOT * HH * 4;
    int* map   = (int*)(ws + off);           off += (size_t)NN * 4;        // 800,000 B
    int* rrow  = (int*)(ws + off);           off += (size_t)TOTSLOT * 4;   // 45,056 B
    unsigned long long* done = (unsigned long long*)(ws + off);            // 64 B

    hipMemsetAsync(map, 0xFF, (size_t)NN * 4, stream);
    hipMemsetAsync(done, 0, 64, stream);
    hipLaunchKernelGGL(k_assign, dim3((TOTSLOT + 255) / 256), dim3(256), 0, stream,
                       u, uneg, map);
    hipLaunchKernelGGL(k_prep, dim3(TOTSLOT), dim3(64), 0, stream,
                       u, uneg, map, z0, zc, rrow);
    hipLaunchKernelGGL(k_main, dim3(BB + COPY_BLOCKS), dim3(256), 0, stream,
                       u, time_delta, time_bar, time_cur, uneg, z0,
                       W_h, b_h, W_e2n, b_e2n, W_re, b_re, W_rn, b_rn,
                       W_t, b_t, W_om, b_om, wtp, alp, psip,
                       zc, rrow, done, out);
    hipLaunchKernelGGL(k_scatter, dim3(TOTSLOT), dim3(64), 0, stream,
                       u, uneg, rrow, zc, out + BB + BB * NEGS);
}